// Round 6
// baseline (17.662 us; speedup 1.0000x reference)
//
#include <hip/hip_runtime.h>
#include <math.h>

#define BATCH 16
#define LSEQ 768
#define NCHUNK 16                 // row-residue classes; grid = 256 blocks = 1/CU
#define NBLK (NCHUNK*BATCH)
#define NT 768                    // one thread per sequence position
#define NWAVE (NT/64)             // 12 waves
#define MAGIC 0x7F3A9C51DEADBEEFull

// ---------- geometry helpers on compacted float4 LDS arrays ----------
// sincos(arccos(x)) = [sqrt(1-x^2), x]  -> no trig needed.

__device__ inline void angle_sc4(const float4* __restrict__ c, int i, float& s, float& co) {
    float4 a = c[i], b = c[i+1], d = c[i+2];
    float v1x = a.x-b.x, v1y = a.y-b.y, v1z = a.z-b.z;
    float v2x = d.x-b.x, v2y = d.y-b.y, v2z = d.z-b.z;
    float dot = v1x*v2x + v1y*v2y + v1z*v2z;
    float n1 = sqrtf(v1x*v1x + v1y*v1y + v1z*v1z);
    float n2 = sqrtf(v2x*v2x + v2y*v2y + v2z*v2z);
    float cv = dot / (n1*n2 + 1e-6f);
    cv = fminf(1.f, fmaxf(-1.f, cv));
    co = cv;
    s  = sqrtf(fmaxf(0.f, 1.f - cv*cv));
}

__device__ inline void dih_sc4(const float4* __restrict__ c, int i, float& s, float& co) {
    float4 p0 = c[i], p1 = c[i+1], p2 = c[i+2], p3 = c[i+3];
    float v1x = p1.x-p0.x, v1y = p1.y-p0.y, v1z = p1.z-p0.z;
    float v2x = p2.x-p1.x, v2y = p2.y-p1.y, v2z = p2.z-p1.z;
    float v3x = p3.x-p2.x, v3y = p3.y-p2.y, v3z = p3.z-p2.z;
    float n1x = v1y*v2z - v1z*v2y, n1y = v1z*v2x - v1x*v2z, n1z = v1x*v2y - v1y*v2x;
    float n2x = v2y*v3z - v2z*v3y, n2y = v2z*v3x - v2x*v3z, n2z = v2x*v3y - v2y*v3x;
    float dot = n1x*n2x + n1y*n2y + n1z*n2z;
    float l1 = sqrtf(n1x*n1x + n1y*n1y + n1z*n1z);
    float l2 = sqrtf(n2x*n2x + n2y*n2y + n2z*n2z);
    float cv = dot / (l1*l2 + 1e-6f);
    cv = fminf(1.f, fmaxf(-1.f, cv));
    float sinp = sqrtf(fmaxf(0.f, 1.f - cv*cv));
    float cx = n1y*n2z - n1z*n2y, cy = n1z*n2x - n1x*n2z, cz = n1x*n2y - n1y*n2x;
    float sg = cx*v2x + cy*v2y + cz*v2z;
    float sgn = (sg > 0.f) ? 1.f : ((sg < 0.f) ? -1.f : 0.f);
    co = cv;
    s  = sgn * sinp;
}

// ---------- single fused kernel, flag-based completion ----------
// Block (c, b): batch b, rows r ≡ c (mod NCHUNK); one thread per seq position.
// Each block: compaction -> pairwise (2x upper triangle) -> angle/torsion slice
// -> normalized float4 partial -> release-store MAGIC flag.
// Block 0: finishes its slice, acquire-spins on all NBLK flags (parallel, one
// per thread), reduces partials in FIXED order (deterministic), writes out,
// resets flags to 0 (so the next call starts clean -- no memset node needed).

__global__ __launch_bounds__(NT) void k_fused(
    const float* __restrict__ pred, const float* __restrict__ targ,
    const int* __restrict__ gm, float4* __restrict__ parts,
    unsigned long long* __restrict__ flags, float* __restrict__ out)
{
    const int b = blockIdx.y;
    const int c = blockIdx.x;
    const int bid = b*NCHUNK + c;
    const int t = threadIdx.x;
    const int lane = t & 63;
    const int wid = t >> 6;

    __shared__ float4 sp[LSEQ];   // compacted pred (xyz + |.|^2)
    __shared__ float4 st[LSEQ];   // compacted target
    __shared__ int   wtot[NWAVE];
    __shared__ float wred[NWAVE][4];

    // --- coalesced mask load + wave-shuffle scan (stable partition) ---
    const int m = gm[b*LSEQ + t];
    int inc = m;
    #pragma unroll
    for (int off = 1; off < 64; off <<= 1) {
        int v = __shfl_up(inc, off);
        if (lane >= off) inc += v;
    }
    if (lane == 63) wtot[wid] = inc;
    __syncthreads();
    int woff = 0, n = 0;
    #pragma unroll
    for (int w = 0; w < NWAVE; ++w) { int v = wtot[w]; n += v; if (w < wid) woff += v; }
    const int d = woff + inc - m;   // exclusive prefix = destination slot

    // zero the padding tail [n, LSEQ) (disjoint from scatter [0,n))
    {
        int j = n + t;
        if (j < LSEQ) {
            sp[j] = make_float4(0.f, 0.f, 0.f, 0.f);
            st[j] = make_float4(0.f, 0.f, 0.f, 0.f);
        }
    }
    if (m) {
        const float* pb = pred + (b*LSEQ + t)*3;
        const float* tb = targ + (b*LSEQ + t)*3;
        float x = pb[0], y = pb[1], z = pb[2];
        sp[d] = make_float4(x, y, z, x*x + y*y + z*z);
        x = tb[0]; y = tb[1]; z = tb[2];
        st[d] = make_float4(x, y, z, x*x + y*y + z*z);
    }
    __syncthreads();

    // --- pairwise dist + clash over upper triangle (doubled) ---
    float dist = 0.f, clash = 0.f;
    for (int r = c; r < n; r += NCHUNK) {
        const int j = r + 1 + t;            // n <= NT -> at most one body
        if (j < n) {
            const float4 ai = sp[r];
            const float4 bi = st[r];
            float4 aj = sp[j];
            float4 bj = st[j];
            float sq1 = fmaxf(ai.w + aj.w - 2.f*(ai.x*aj.x + ai.y*aj.y + ai.z*aj.z), 1e-12f);
            float d1  = sqrtf(sq1);
            float sq2 = fmaxf(bi.w + bj.w - 2.f*(bi.x*bj.x + bi.y*bj.y + bi.z*bj.z), 1e-12f);
            float d2  = sqrtf(sq2);
            float dd = d1 - d2;
            dist += dd*dd;
            if (d1 < 3.8f && d1 > 2.0f) { float cv = 3.8f - d1; clash += cv*cv; }
        }
    }

    // --- angle + torsion, i ≡ c (mod NCHUNK): one eval per thread (t < 48) ---
    float aacc = 0.f, tacc = 0.f;
    if (t < LSEQ/NCHUNK) {
        const int i = c + NCHUNK*t;
        if (i < LSEQ-2 && i + 1 < n) {
            float s1, c1, s2, c2;
            angle_sc4(sp, i, s1, c1);
            angle_sc4(st, i, s2, c2);
            float ds = s1 - s2, dc = c1 - c2;
            aacc = ds*ds + dc*dc;
        }
        if (i < LSEQ-3 && i + 2 < n) {
            float s1, c1, s2, c2;
            dih_sc4(sp, i, s1, c1);
            dih_sc4(st, i, s2, c2);
            float ds = s1 - s2, dc = c1 - c2;
            tacc = ds*ds + dc*dc;
        }
    }

    // --- block reduction of (dist, clash, angle, torsion) ---
    #pragma unroll
    for (int off = 32; off; off >>= 1) {
        dist  += __shfl_down(dist,  off);
        clash += __shfl_down(clash, off);
        aacc  += __shfl_down(aacc,  off);
        tacc  += __shfl_down(tacc,  off);
    }
    if (lane == 0) { wred[wid][0]=dist; wred[wid][1]=clash; wred[wid][2]=aacc; wred[wid][3]=tacc; }
    __syncthreads();
    if (t == 0) {
        float ds = 0.f, cs = 0.f, as = 0.f, ts = 0.f;
        #pragma unroll
        for (int w = 0; w < NWAVE; ++w) { ds += wred[w][0]; cs += wred[w][1]; as += wred[w][2]; ts += wred[w][3]; }
        float denom = (float)n * (float)n + 1e-8f;
        int cai = n - 1; if (cai < 0) cai = 0; if (cai > LSEQ-2) cai = LSEQ-2;
        int cti = n - 2; if (cti < 0) cti = 0; if (cti > LSEQ-3) cti = LSEQ-3;
        parts[bid] = make_float4(2.f*ds/denom, 2.f*cs/denom,
                                 as / fmaxf((float)cai, 1e-6f),
                                 ts / fmaxf((float)cti, 1e-6f));
        // release: parts[bid] visible before the flag
        __hip_atomic_store(&flags[bid], MAGIC, __ATOMIC_RELEASE,
                           __HIP_MEMORY_SCOPE_AGENT);
    }

    if (bid != 0) return;

    // --- block 0: wait for all partials (parallel spin, one flag/thread) ---
    if (t < NBLK) {
        while (__hip_atomic_load(&flags[t], __ATOMIC_ACQUIRE,
                                 __HIP_MEMORY_SCOPE_AGENT) != MAGIC) {
            __builtin_amdgcn_s_sleep(1);
        }
    }
    __syncthreads();   // all flags seen; also guards wred reuse below

    // --- deterministic final reduce (fixed order over parts) ---
    float fd = 0.f, fc = 0.f, fa = 0.f, ft = 0.f;
    if (t < NBLK) {
        float4 p = parts[t];
        fd = p.x; fc = p.y; fa = p.z; ft = p.w;
    }
    #pragma unroll
    for (int off = 32; off; off >>= 1) {
        fd += __shfl_down(fd, off);
        fc += __shfl_down(fc, off);
        fa += __shfl_down(fa, off);
        ft += __shfl_down(ft, off);
    }
    if (lane == 0) { wred[wid][0]=fd; wred[wid][1]=fc; wred[wid][2]=fa; wred[wid][3]=ft; }
    __syncthreads();
    if (t == 0) {
        float d_ = 0.f, c_ = 0.f, a_ = 0.f, t_ = 0.f;
        #pragma unroll
        for (int w = 0; w < NWAVE; ++w) { d_ += wred[w][0]; c_ += wred[w][1]; a_ += wred[w][2]; t_ += wred[w][3]; }
        out[0] = a_ / (float)BATCH;
        out[1] = t_ / (float)BATCH;
        out[2] = d_ / (float)BATCH;
        out[3] = d_ / (float)BATCH;   // inter_dist_loss aliases dist_loss
        out[4] = c_ / (float)BATCH;
    }

    // --- reset flags so the NEXT call starts clean (no memset node) ---
    if (t < NBLK) {
        __hip_atomic_store(&flags[t], 0ull, __ATOMIC_RELAXED,
                           __HIP_MEMORY_SCOPE_AGENT);
    }
}

extern "C" void kernel_launch(void* const* d_in, const int* in_sizes, int n_in,
                              void* d_out, int out_size, void* d_ws, size_t ws_size,
                              hipStream_t stream) {
    (void)in_sizes; (void)n_in; (void)out_size; (void)ws_size;
    const float* pred = (const float*)d_in[0];
    const float* targ = (const float*)d_in[1];
    const int*   gm   = (const int*)d_in[2];
    // d_in[3] (poc) and d_in[4] (poc_mask) are dead in the reference.

    float4*             parts = (float4*)d_ws;                 // NBLK entries
    unsigned long long* flags = (unsigned long long*)(parts + NBLK); // NBLK entries
    float*              out   = (float*)d_out;

    k_fused<<<dim3(NCHUNK, BATCH), NT, 0, stream>>>(pred, targ, gm, parts, flags, out);
}

// Round 7
// 14.614 us; speedup vs baseline: 1.2086x; 1.2086x over previous
//
#include <hip/hip_runtime.h>
#include <math.h>

#define BATCH 16
#define LSEQ 768
#define NCHUNK 16                 // row-residue classes; grid = 256 blocks = 1/CU
#define NBLK (NCHUNK*BATCH)
#define NT 768                    // one thread per sequence position
#define NWAVE (NT/64)             // 12 waves

// ---------- geometry helpers on compacted float4 LDS arrays ----------
// sincos(arccos(x)) = [sqrt(1-x^2), x]  -> no trig needed.

__device__ inline void angle_sc4(const float4* __restrict__ c, int i, float& s, float& co) {
    float4 a = c[i], b = c[i+1], d = c[i+2];
    float v1x = a.x-b.x, v1y = a.y-b.y, v1z = a.z-b.z;
    float v2x = d.x-b.x, v2y = d.y-b.y, v2z = d.z-b.z;
    float dot = v1x*v2x + v1y*v2y + v1z*v2z;
    float n1 = sqrtf(v1x*v1x + v1y*v1y + v1z*v1z);
    float n2 = sqrtf(v2x*v2x + v2y*v2y + v2z*v2z);
    float cv = dot / (n1*n2 + 1e-6f);
    cv = fminf(1.f, fmaxf(-1.f, cv));
    co = cv;
    s  = sqrtf(fmaxf(0.f, 1.f - cv*cv));
}

__device__ inline void dih_sc4(const float4* __restrict__ c, int i, float& s, float& co) {
    float4 p0 = c[i], p1 = c[i+1], p2 = c[i+2], p3 = c[i+3];
    float v1x = p1.x-p0.x, v1y = p1.y-p0.y, v1z = p1.z-p0.z;
    float v2x = p2.x-p1.x, v2y = p2.y-p1.y, v2z = p2.z-p1.z;
    float v3x = p3.x-p2.x, v3y = p3.y-p2.y, v3z = p3.z-p2.z;
    float n1x = v1y*v2z - v1z*v2y, n1y = v1z*v2x - v1x*v2z, n1z = v1x*v2y - v1y*v2x;
    float n2x = v2y*v3z - v2z*v3y, n2y = v2z*v3x - v2x*v3z, n2z = v2x*v3y - v2y*v3x;
    float dot = n1x*n2x + n1y*n2y + n1z*n2z;
    float l1 = sqrtf(n1x*n1x + n1y*n1y + n1z*n1z);
    float l2 = sqrtf(n2x*n2x + n2y*n2y + n2z*n2z);
    float cv = dot / (l1*l2 + 1e-6f);
    cv = fminf(1.f, fmaxf(-1.f, cv));
    float sinp = sqrtf(fmaxf(0.f, 1.f - cv*cv));
    float cx = n1y*n2z - n1z*n2y, cy = n1z*n2x - n1x*n2z, cz = n1x*n2y - n1y*n2x;
    float sg = cx*v2x + cy*v2y + cz*v2z;
    float sgn = (sg > 0.f) ? 1.f : ((sg < 0.f) ? -1.f : 0.f);
    co = cv;
    s  = sgn * sinp;
}

// ---------- kernel 1: per-block compaction + symmetric pairwise ----------
// Block (c, b): batch b. One thread per sequence position (NT=768, 12 waves).
//  * stable compaction into LDS (coalesced loads, shuffle scan)
//  * pairwise: thread t OWNS column j=t in REGISTERS (loaded once); loop over
//    rows r ≡ c (mod NCHUNK); body = 2 broadcast LDS reads + VALU, predicate
//    t>r && t<n covers the upper triangle exactly (doubled for full sum)
//  * angle/torsion for chain positions i ≡ c (mod NCHUNK), one eval/thread
//  * block writes one fully-normalized float4 partial.

__global__ __launch_bounds__(NT) void k_main(
    const float* __restrict__ pred, const float* __restrict__ targ,
    const int* __restrict__ gm, float4* __restrict__ parts)
{
    const int b = blockIdx.y;
    const int c = blockIdx.x;
    const int t = threadIdx.x;
    const int lane = t & 63;
    const int wid = t >> 6;

    __shared__ float4 sp[LSEQ];   // compacted pred (xyz + |.|^2)
    __shared__ float4 st[LSEQ];   // compacted target
    __shared__ int   wtot[NWAVE];
    __shared__ float wred[NWAVE][4];

    // --- coalesced mask load + wave-shuffle scan (stable partition) ---
    const int m = gm[b*LSEQ + t];
    int inc = m;
    #pragma unroll
    for (int off = 1; off < 64; off <<= 1) {
        int v = __shfl_up(inc, off);
        if (lane >= off) inc += v;
    }
    if (lane == 63) wtot[wid] = inc;
    __syncthreads();
    int woff = 0, n = 0;
    #pragma unroll
    for (int w = 0; w < NWAVE; ++w) { int v = wtot[w]; n += v; if (w < wid) woff += v; }
    const int d = woff + inc - m;   // exclusive prefix = destination slot

    // zero the padding tail [n, LSEQ) (disjoint from scatter [0,n))
    {
        int j = n + t;
        if (j < LSEQ) {
            sp[j] = make_float4(0.f, 0.f, 0.f, 0.f);
            st[j] = make_float4(0.f, 0.f, 0.f, 0.f);
        }
    }
    if (m) {
        const float* pb = pred + (b*LSEQ + t)*3;
        const float* tb = targ + (b*LSEQ + t)*3;
        float x = pb[0], y = pb[1], z = pb[2];
        sp[d] = make_float4(x, y, z, x*x + y*y + z*z);
        x = tb[0]; y = tb[1]; z = tb[2];
        st[d] = make_float4(x, y, z, x*x + y*y + z*z);
    }
    __syncthreads();

    // --- column j = t lives in registers for the whole pairwise phase ---
    const float4 aj = sp[t];
    const float4 bj = st[t];
    const bool jlive = (t < n);

    // --- pairwise dist + clash over upper triangle (doubled) ---
    float dist = 0.f, clash = 0.f;
    for (int r = c; r < n; r += NCHUNK) {
        const float4 ai = sp[r];   // broadcast read (conflict-free)
        const float4 bi = st[r];   // broadcast read
        if (jlive && t > r) {
            float sq1 = fmaxf(ai.w + aj.w - 2.f*(ai.x*aj.x + ai.y*aj.y + ai.z*aj.z), 1e-12f);
            float d1  = sqrtf(sq1);
            float sq2 = fmaxf(bi.w + bj.w - 2.f*(bi.x*bj.x + bi.y*bj.y + bi.z*bj.z), 1e-12f);
            float d2  = sqrtf(sq2);
            float dd = d1 - d2;
            dist += dd*dd;
            if (d1 < 3.8f && d1 > 2.0f) { float cv = 3.8f - d1; clash += cv*cv; }
        }
    }

    // --- angle + torsion, i ≡ c (mod NCHUNK): one eval per thread (t < 48) ---
    float aacc = 0.f, tacc = 0.f;
    if (t < LSEQ/NCHUNK) {
        const int i = c + NCHUNK*t;
        if (i < LSEQ-2 && i + 1 < n) {
            float s1, c1, s2, c2;
            angle_sc4(sp, i, s1, c1);
            angle_sc4(st, i, s2, c2);
            float ds = s1 - s2, dc = c1 - c2;
            aacc = ds*ds + dc*dc;
        }
        if (i < LSEQ-3 && i + 2 < n) {
            float s1, c1, s2, c2;
            dih_sc4(sp, i, s1, c1);
            dih_sc4(st, i, s2, c2);
            float ds = s1 - s2, dc = c1 - c2;
            tacc = ds*ds + dc*dc;
        }
    }

    // --- block reduction of (dist, clash, angle, torsion) ---
    #pragma unroll
    for (int off = 32; off; off >>= 1) {
        dist  += __shfl_down(dist,  off);
        clash += __shfl_down(clash, off);
        aacc  += __shfl_down(aacc,  off);
        tacc  += __shfl_down(tacc,  off);
    }
    if (lane == 0) { wred[wid][0]=dist; wred[wid][1]=clash; wred[wid][2]=aacc; wred[wid][3]=tacc; }
    __syncthreads();
    if (t == 0) {
        float ds = 0.f, cs = 0.f, as = 0.f, ts = 0.f;
        #pragma unroll
        for (int w = 0; w < NWAVE; ++w) { ds += wred[w][0]; cs += wred[w][1]; as += wred[w][2]; ts += wred[w][3]; }
        float denom = (float)n * (float)n + 1e-8f;
        int cai = n - 1; if (cai < 0) cai = 0; if (cai > LSEQ-2) cai = LSEQ-2;
        int cti = n - 2; if (cti < 0) cti = 0; if (cti > LSEQ-3) cti = LSEQ-3;
        parts[b*NCHUNK + c] = make_float4(2.f*ds/denom, 2.f*cs/denom,
                                          as / fmaxf((float)cai, 1e-6f),
                                          ts / fmaxf((float)cti, 1e-6f));
    }
}

// ---------- kernel 2: deterministic final reduce (1 block) ----------

__global__ __launch_bounds__(256) void k_final(
    const float4* __restrict__ parts, float* __restrict__ out)
{
    const int t = threadIdx.x;
    const int lane = t & 63;
    const int wid = t >> 6;
    __shared__ float wred[4][4];

    float4 p = parts[t];           // exactly NBLK == 256 entries
    float fd = p.x, fc = p.y, fa = p.z, ft = p.w;
    #pragma unroll
    for (int off = 32; off; off >>= 1) {
        fd += __shfl_down(fd, off);
        fc += __shfl_down(fc, off);
        fa += __shfl_down(fa, off);
        ft += __shfl_down(ft, off);
    }
    if (lane == 0) { wred[wid][0]=fd; wred[wid][1]=fc; wred[wid][2]=fa; wred[wid][3]=ft; }
    __syncthreads();
    if (t == 0) {
        float d_ = 0.f, c_ = 0.f, a_ = 0.f, t_ = 0.f;
        #pragma unroll
        for (int w = 0; w < 4; ++w) { d_ += wred[w][0]; c_ += wred[w][1]; a_ += wred[w][2]; t_ += wred[w][3]; }
        out[0] = a_ / (float)BATCH;
        out[1] = t_ / (float)BATCH;
        out[2] = d_ / (float)BATCH;
        out[3] = d_ / (float)BATCH;   // inter_dist_loss aliases dist_loss
        out[4] = c_ / (float)BATCH;
    }
}

extern "C" void kernel_launch(void* const* d_in, const int* in_sizes, int n_in,
                              void* d_out, int out_size, void* d_ws, size_t ws_size,
                              hipStream_t stream) {
    (void)in_sizes; (void)n_in; (void)out_size; (void)ws_size;
    const float* pred = (const float*)d_in[0];
    const float* targ = (const float*)d_in[1];
    const int*   gm   = (const int*)d_in[2];
    // d_in[3] (poc) and d_in[4] (poc_mask) are dead in the reference.

    float4* parts = (float4*)d_ws;              // NBLK entries
    float*  out   = (float*)d_out;

    k_main<<<dim3(NCHUNK, BATCH), NT, 0, stream>>>(pred, targ, gm, parts);
    k_final<<<1, 256, 0, stream>>>(parts, out);
}